// Round 7
// baseline (238.433 us; speedup 1.0000x reference)
//
#include <hip/hip_runtime.h>
#include <hip/hip_bf16.h>

#define BATCH 32
#define HW1 224

typedef __attribute__((ext_vector_type(8))) short short8;
typedef __attribute__((ext_vector_type(4))) float floatx4;

static __device__ __forceinline__ unsigned short f2bf(float f) {
    unsigned int u = __float_as_uint(f);
    unsigned int r = (u + 0x7fffu + ((u >> 16) & 1u)) >> 16;   // RNE
    return (unsigned short)r;
}

static __device__ __forceinline__ float2 fma2(float w, float2 p, float2 a) {
    a.x = fmaf(w, p.x, a.x);
    a.y = fmaf(w, p.y, a.y);
    return a;
}

// ---------------------------------------------------------------------------
// Kernel A1: BN const folding + feat zero. One block, tiny.
// ---------------------------------------------------------------------------
__global__ __launch_bounds__(256) void gen_small(
    const float* __restrict__ wb, const float* __restrict__ bb,
    const float* __restrict__ conv2_b, const float* __restrict__ conv3_b,
    const float* __restrict__ bn1_g, const float* __restrict__ bn1_b,
    const float* __restrict__ bn1_m, const float* __restrict__ bn1_v,
    const float* __restrict__ bn2_g, const float* __restrict__ bn2_b,
    const float* __restrict__ bn2_m, const float* __restrict__ bn2_v,
    const float* __restrict__ bn3_g, const float* __restrict__ bn3_b,
    const float* __restrict__ bn3_m, const float* __restrict__ bn3_v,
    float* __restrict__ bn1_s, float* __restrict__ bn1_t,
    float* __restrict__ bn2_s, float* __restrict__ bn2_t,
    float* __restrict__ bn3_s, float* __restrict__ bn3_t,
    float* __restrict__ feat)
{
    const int t = threadIdx.x;
    if (t < 32) {
        float dynb = bb[t] + wb[t*3+0] + wb[t*3+1] + wb[t*3+2];
        float s = bn1_g[t] / sqrtf(bn1_v[t] + 1e-5f);
        bn1_s[t] = s;
        bn1_t[t] = (dynb - bn1_m[t]) * s + bn1_b[t];
    }
    if (t < 64) {
        float s = bn2_g[t] / sqrtf(bn2_v[t] + 1e-5f);
        bn2_s[t] = s;
        bn2_t[t] = (conv2_b[t] - bn2_m[t]) * s + bn2_b[t];
    }
    if (t < 128) {
        float s = bn3_g[t] / sqrtf(bn3_v[t] + 1e-5f);
        bn3_s[t] = s;
        bn3_t[t] = (conv3_b[t] - bn3_m[t]) * s + bn3_b[t];
    }
    for (int i = t; i < BATCH*128; i += 256) feat[i] = 0.f;
}

// ---------------------------------------------------------------------------
// Kernel A2: blocks [0,216): recompute h1/h2 locally (w2 from L2), then
// dwt[tap][oc] = (W3 @ h2 + b3) transposed, wave-per-row dot.
// Blocks [216,576): conv2/conv3 weight repack to [tap][OC][IC] bf16.
// ---------------------------------------------------------------------------
__global__ __launch_bounds__(256) void gen_dynw_repack(
    const float* __restrict__ w1, const float* __restrict__ b1,
    const float* __restrict__ w2, const float* __restrict__ b2,
    const float* __restrict__ w3, const float* __restrict__ b3,
    const float* __restrict__ conv2_w, const float* __restrict__ conv3_w,
    float* __restrict__ dwt,
    unsigned short* __restrict__ wrep2, unsigned short* __restrict__ wrep3)
{
    __shared__ float h1s[128];
    __shared__ float h2s[256];
    const int blk = blockIdx.x;
    const int t = threadIdx.x;
    if (blk < 216) {
        if (t < 128) {
            float s = b1[t] + w1[t*3+0] + w1[t*3+1] + w1[t*3+2];
            h1s[t] = fmaxf(s, 0.f);
        }
        __syncthreads();
        {
            float s = b2[t];
            const float* wr = w2 + (size_t)t*128;
#pragma unroll 4
            for (int k = 0; k < 128; k += 4) {
                float4 wv = *(const float4*)(wr + k);
                s = fmaf(wv.x, h1s[k  ], s);
                s = fmaf(wv.y, h1s[k+1], s);
                s = fmaf(wv.z, h1s[k+2], s);
                s = fmaf(wv.w, h1s[k+3], s);
            }
            h2s[t] = fmaxf(s, 0.f);
        }
        __syncthreads();
        const int wave = t >> 6, lane = t & 63;
        const int row = blk*4 + wave;          // row = oc*27 + tap
        float4 wv = *(const float4*)(w3 + (size_t)row*256 + lane*4);
        float4 hv = *(const float4*)&h2s[lane*4];
        float s = wv.x*hv.x + wv.y*hv.y + wv.z*hv.z + wv.w*hv.w;
#pragma unroll
        for (int m = 1; m < 64; m <<= 1) s += __shfl_xor(s, m);
        if (lane == 0) {
            int oc = row / 27, tap = row - oc*27;
            dwt[tap*32 + oc] = s + b3[row];
        }
    } else {
        const int i = (blk - 216)*256 + t;
        const int N2 = 9*64*32;   // 18432
        if (i < N2) {
            int tp = i / (64*32); int rem = i - tp*(64*32);
            int oc = rem >> 5, ic = rem & 31;
            wrep2[i] = f2bf(conv2_w[(oc*32 + ic)*9 + tp]);
        } else {
            int j = i - N2;       // j < 9*128*64
            int tp = j / (128*64); int rem = j - tp*(128*64);
            int oc = rem >> 6, ic = rem & 63;
            wrep3[j] = f2bf(conv3_w[(oc*64 + ic)*9 + tp]);
        }
    }
}

// ---------------------------------------------------------------------------
// Kernel B: conv1 (3->32, 224x224, pad1) + bn + relu + 2x2 maxpool.
// amdgpu_waves_per_eu(2,8): legalizes up to 256 VGPR so the allocator may
// keep patch (48) + acc (64) resident (R4-R6 lesson: default heuristic pins
// VGPR=36 and re-reads LDS per oc-group; asm pins got parked in AGPRs).
// 2 groups x 16 oc; acc as float2 pairs (invites v_pk_fma_f32).
// Output bf16 channel-last act1[b][112][112][32].
// ---------------------------------------------------------------------------
__global__ __launch_bounds__(256)
__attribute__((amdgpu_waves_per_eu(2, 8)))
void conv1_pool(
    const float* __restrict__ x, const float* __restrict__ dwt,
    const float* __restrict__ bn_s, const float* __restrict__ bn_t,
    unsigned short* __restrict__ act1)
{
    constexpr int PS = 36;
    __shared__ __align__(16) float sp[3*34*PS];     // 14688 B

    const int tid = threadIdx.x;
    const int bx = blockIdx.x, by = blockIdx.y, b = blockIdx.z;
    const int gx0 = bx*32 - 1, gy0 = by*32 - 1;
    const float* xb = x + (size_t)b * 3 * HW1 * HW1;

    for (int i = tid; i < 3*34*34; i += 256) {
        int ch = i / 1156; int rem = i - ch*1156;
        int r = rem / 34, c = rem - r*34;
        int gy = gy0 + r, gx = gx0 + c;
        float v = 0.f;
        if ((unsigned)gy < HW1 && (unsigned)gx < HW1)
            v = xb[(ch*HW1 + gy)*HW1 + gx];
        sp[(ch*34 + r)*PS + c] = v;
    }
    __syncthreads();

    const int tx = tid & 15, ty = tid >> 4;

    float p[3][4][4];                   // resident patch, 48 VGPRs
#pragma unroll
    for (int ch = 0; ch < 3; ++ch)
#pragma unroll
        for (int r = 0; r < 4; ++r) {
            const float* rp = &sp[(ch*34 + 2*ty + r)*PS + 2*tx];
            float2 a  = *(const float2*)rp;
            float2 bq = *(const float2*)(rp + 2);
            p[ch][r][0] = a.x;  p[ch][r][1] = a.y;
            p[ch][r][2] = bq.x; p[ch][r][3] = bq.y;
        }
#pragma unroll
    for (int ch = 0; ch < 3; ++ch)
#pragma unroll
        for (int r = 0; r < 4; ++r)
#pragma unroll
            for (int c = 0; c < 4; ++c)
                asm volatile("" : "+v"(p[ch][r][c]));

    const int py = by*16 + ty, px = bx*16 + tx;
    unsigned short* dst = act1 + ((size_t)((b*112 + py)*112 + px))*32;

#pragma unroll 1
    for (int g = 0; g < 2; ++g) {            // 16 oc per group
        float2 acc[16][2];
#pragma unroll
        for (int o = 0; o < 16; ++o) {
            acc[o][0] = make_float2(0.f, 0.f);
            acc[o][1] = make_float2(0.f, 0.f);
        }

#pragma unroll
        for (int ch = 0; ch < 3; ++ch)
#pragma unroll
            for (int ky = 0; ky < 3; ++ky)
#pragma unroll
                for (int kx = 0; kx < 3; ++kx) {
                    const float* wp = &dwt[(ch*9 + ky*3 + kx)*32 + g*16];
                    float2 pv0 = make_float2(p[ch][ky  ][kx], p[ch][ky  ][kx+1]);
                    float2 pv1 = make_float2(p[ch][ky+1][kx], p[ch][ky+1][kx+1]);
#pragma unroll
                    for (int o = 0; o < 16; ++o) {
                        float w = wp[o];      // uniform -> SGPR operand
                        acc[o][0] = fma2(w, pv0, acc[o][0]);
                        acc[o][1] = fma2(w, pv1, acc[o][1]);
                    }
                }

        unsigned int pk[4];
#pragma unroll
        for (int o = 0; o < 16; ++o) {
            int oc = g*16 + o;
            float s = bn_s[oc], t = bn_t[oc];
            float m = fmaxf(fmaxf(fmaf(acc[o][0].x, s, t), fmaf(acc[o][0].y, s, t)),
                            fmaxf(fmaf(acc[o][1].x, s, t), fmaf(acc[o][1].y, s, t)));
            m = fmaxf(m, 0.f);
            unsigned short us = f2bf(m);
            if (o & 1) pk[(o >> 1) & 3] |= ((unsigned int)us) << 16;
            else       pk[(o >> 1) & 3]  = us;
            if ((o & 7) == 7)
                *(uint4*)(dst + g*16 + (o >> 3)*8) = *(uint4*)pk;
        }
    }
}

// ---------------------------------------------------------------------------
// Kernel C: conv2 (32->64, 112x112) bf16 MFMA + bn + relu + 2x2 maxpool.
// Rolling-row-window: 54 ds_read_b128/wave, 144 MFMA.
// ---------------------------------------------------------------------------
__global__ __launch_bounds__(256) void conv2_mfma(
    const unsigned short* __restrict__ act1,
    const unsigned short* __restrict__ wrep,
    const float* __restrict__ bn_s, const float* __restrict__ bn_t,
    unsigned short* __restrict__ act2)
{
    constexpr int IC = 32, OC = 64, H = 112;
    __shared__ __align__(16) short lds[4*18*18*8];   // [chunk][y][x][8ic]

    const int tid = threadIdx.x;
    const int b = blockIdx.z;
    const int cx0 = blockIdx.x*16, cy0 = blockIdx.y*16;
    const unsigned short* ab = act1 + (size_t)b*H*H*IC;

    for (int s = tid; s < 4*324; s += 256) {
        int ck = s / 324; int rem = s - ck*324;
        int y = rem / 18, xx = rem - y*18;
        int gy = cy0 - 1 + y, gx = cx0 - 1 + xx;
        uint4 v = {0,0,0,0};
        if ((unsigned)gy < H && (unsigned)gx < H)
            v = *(const uint4*)(ab + (size_t)(gy*H + gx)*IC + ck*8);
        *(uint4*)&lds[s*8] = v;
    }

    const int lane = tid & 63, wave = tid >> 6;
    const int n = lane & 15, quad = lane >> 4;
    const int oc0w = wave * 16;

    short8 afr[9];
#pragma unroll
    for (int t = 0; t < 9; ++t)
        afr[t] = *(const short8*)(wrep + (size_t)(t*OC + oc0w + n)*IC + quad*8);

    float4 sv = *(const float4*)(bn_s + oc0w + quad*4);
    float4 tv = *(const float4*)(bn_t + oc0w + quad*4);
    float sj[4] = {sv.x, sv.y, sv.z, sv.w};
    float tj[4] = {tv.x, tv.y, tv.z, tv.w};

    __syncthreads();

    floatx4 acc[3];
    float ev[4];      // saved even-row post-relu values awaiting odd partner

#pragma unroll
    for (int r = 0; r < 18; ++r) {
        const short* rp = &lds[((quad*18 + r)*18 + n)*8];
        short8 w0 = *(const short8*)(rp);
        short8 w1 = *(const short8*)(rp + 8);
        short8 w2 = *(const short8*)(rp + 16);

        if (r < 16) {                    // ky=0 for y=r (init)
            floatx4 a = {0.f,0.f,0.f,0.f};
            a = __builtin_amdgcn_mfma_f32_16x16x32_bf16(afr[0], w0, a, 0, 0, 0);
            a = __builtin_amdgcn_mfma_f32_16x16x32_bf16(afr[1], w1, a, 0, 0, 0);
            a = __builtin_amdgcn_mfma_f32_16x16x32_bf16(afr[2], w2, a, 0, 0, 0);
            acc[r % 3] = a;
        }
        if (r >= 1 && r <= 16) {         // ky=1 for y=r-1
            int y = r - 1;
            floatx4 a = acc[y % 3];
            a = __builtin_amdgcn_mfma_f32_16x16x32_bf16(afr[3], w0, a, 0, 0, 0);
            a = __builtin_amdgcn_mfma_f32_16x16x32_bf16(afr[4], w1, a, 0, 0, 0);
            a = __builtin_amdgcn_mfma_f32_16x16x32_bf16(afr[5], w2, a, 0, 0, 0);
            acc[y % 3] = a;
        }
        if (r >= 2) {                    // ky=2 for y=r-2, then finalize
            int y = r - 2;
            floatx4 a = acc[y % 3];
            a = __builtin_amdgcn_mfma_f32_16x16x32_bf16(afr[6], w0, a, 0, 0, 0);
            a = __builtin_amdgcn_mfma_f32_16x16x32_bf16(afr[7], w1, a, 0, 0, 0);
            a = __builtin_amdgcn_mfma_f32_16x16x32_bf16(afr[8], w2, a, 0, 0, 0);

            float v[4];
#pragma unroll
            for (int j = 0; j < 4; ++j)
                v[j] = fmaxf(fmaf(a[j], sj[j], tj[j]), 0.f);

            if ((y & 1) == 0) {
#pragma unroll
                for (int j = 0; j < 4; ++j) ev[j] = v[j];
            } else {
                unsigned int pk[2];
#pragma unroll
                for (int j = 0; j < 4; ++j) {
                    float m = fmaxf(v[j], ev[j]);
                    m = fmaxf(m, __shfl_xor(m, 1));
                    unsigned short us = f2bf(m);
                    if (j & 1) pk[j >> 1] |= ((unsigned int)us) << 16;
                    else       pk[j >> 1]  = us;
                }
                if (!(n & 1)) {
                    int py = (cy0 >> 1) + (y >> 1), px = (cx0 >> 1) + (n >> 1);
                    unsigned short* dstp =
                        act2 + ((size_t)((b*56 + py)*56 + px))*OC + oc0w + quad*4;
                    *(uint2*)dstp = *(uint2*)pk;
                }
            }
        }
    }
}

// ---------------------------------------------------------------------------
// Kernel D: conv3 (64->128, 56x56) bf16 MFMA + bn + relu + spatial mean sum.
// ---------------------------------------------------------------------------
__global__ __launch_bounds__(256) void conv3_mfma(
    const unsigned short* __restrict__ act2,
    const unsigned short* __restrict__ wrep,
    const float* __restrict__ bn_s, const float* __restrict__ bn_t,
    float* __restrict__ feat)
{
    constexpr int IC = 64, OC = 128, H = 56;
    __shared__ __align__(16) short lds[8*18*18*8];

    const int tid = threadIdx.x;
    const int b = blockIdx.z >> 1, half = blockIdx.z & 1;
    const int cx0 = blockIdx.x*16, cy0 = blockIdx.y*16;
    const unsigned short* ab = act2 + (size_t)b*H*H*IC;

    for (int s = tid; s < 8*324; s += 256) {
        int ck = s / 324; int rem = s - ck*324;
        int y = rem / 18, xx = rem - y*18;
        int gy = cy0 - 1 + y, gx = cx0 - 1 + xx;
        uint4 v = {0,0,0,0};
        if ((unsigned)gy < H && (unsigned)gx < H)
            v = *(const uint4*)(ab + (size_t)(gy*H + gx)*IC + ck*8);
        *(uint4*)&lds[s*8] = v;
    }

    const int lane = tid & 63, wave = tid >> 6;
    const int n = lane & 15, quad = lane >> 4;
    const int oc0w = half*64 + wave*16;

    short8 afr[18];
#pragma unroll
    for (int t = 0; t < 9; ++t)
#pragma unroll
        for (int kc = 0; kc < 2; ++kc)
            afr[t*2 + kc] = *(const short8*)(wrep + (size_t)(t*OC + oc0w + n)*IC + kc*32 + quad*8);

    float4 sv = *(const float4*)(bn_s + oc0w + quad*4);
    float4 tv = *(const float4*)(bn_t + oc0w + quad*4);

    __syncthreads();

    float sum[4] = {0.f, 0.f, 0.f, 0.f};
    const bool vx = (cx0 + n) < H;
    const int ymax = (H - cy0) < 16 ? (H - cy0) : 16;
    float sj[4] = {sv.x, sv.y, sv.z, sv.w};
    float tj[4] = {tv.x, tv.y, tv.z, tv.w};

    for (int y = 0; y < ymax; ++y) {
        floatx4 acc0 = {0.f,0.f,0.f,0.f};
        floatx4 acc1 = {0.f,0.f,0.f,0.f};
#pragma unroll
        for (int ky = 0; ky < 3; ++ky)
#pragma unroll
            for (int kx = 0; kx < 3; ++kx) {
                int t = ky*3 + kx;
                short8 b0 = *(const short8*)&lds[(((0*4 + quad)*18 + y+ky)*18 + n+kx)*8];
                short8 b1 = *(const short8*)&lds[(((1*4 + quad)*18 + y+ky)*18 + n+kx)*8];
                acc0 = __builtin_amdgcn_mfma_f32_16x16x32_bf16(afr[t*2+0], b0, acc0, 0, 0, 0);
                acc1 = __builtin_amdgcn_mfma_f32_16x16x32_bf16(afr[t*2+1], b1, acc1, 0, 0, 0);
            }
        if (vx) {
#pragma unroll
            for (int j = 0; j < 4; ++j)
                sum[j] += fmaxf(fmaf(acc0[j] + acc1[j], sj[j], tj[j]), 0.f);
        }
    }
#pragma unroll
    for (int j = 0; j < 4; ++j) {
        sum[j] += __shfl_xor(sum[j], 1);
        sum[j] += __shfl_xor(sum[j], 2);
        sum[j] += __shfl_xor(sum[j], 4);
        sum[j] += __shfl_xor(sum[j], 8);
    }
    if (n == 0) {
#pragma unroll
        for (int j = 0; j < 4; ++j)
            atomicAdd(&feat[b*128 + oc0w + quad*4 + j], sum[j]);
    }
}

// ---------------------------------------------------------------------------
// Kernel E: FC head.
// ---------------------------------------------------------------------------
__global__ __launch_bounds__(256) void fc_kernel(
    const float* __restrict__ feat, const float* __restrict__ fc_w,
    const float* __restrict__ fc_b, float* __restrict__ out)
{
    int i = blockIdx.x * 256 + threadIdx.x;
    if (i >= BATCH*100) return;
    int b = i / 100, n = i - b*100;
    const float* f = feat + b*128;
    const float* w = fc_w + n*128;
    float s = 0.f;
#pragma unroll 4
    for (int k = 0; k < 128; ++k) s = fmaf(f[k], w[k], s);
    out[i] = s * (1.f/3136.f) + fc_b[n];
}

extern "C" void kernel_launch(void* const* d_in, const int* in_sizes, int n_in,
                              void* d_out, int out_size, void* d_ws, size_t ws_size,
                              hipStream_t stream)
{
    const float* x       = (const float*)d_in[0];
    const float* w1      = (const float*)d_in[1];
    const float* b1      = (const float*)d_in[2];
    const float* w2      = (const float*)d_in[3];
    const float* b2      = (const float*)d_in[4];
    const float* w3      = (const float*)d_in[5];
    const float* b3      = (const float*)d_in[6];
    const float* wb      = (const float*)d_in[7];
    const float* bb      = (const float*)d_in[8];
    const float* conv2_w = (const float*)d_in[9];
    const float* conv2_b = (const float*)d_in[10];
    const float* conv3_w = (const float*)d_in[11];
    const float* conv3_b = (const float*)d_in[12];
    const float* bn1_g = (const float*)d_in[13];
    const float* bn1_b = (const float*)d_in[14];
    const float* bn1_m = (const float*)d_in[15];
    const float* bn1_v = (const float*)d_in[16];
    const float* bn2_g = (const float*)d_in[17];
    const float* bn2_b = (const float*)d_in[18];
    const float* bn2_m = (const float*)d_in[19];
    const float* bn2_v = (const float*)d_in[20];
    const float* bn3_g = (const float*)d_in[21];
    const float* bn3_b = (const float*)d_in[22];
    const float* bn3_m = (const float*)d_in[23];
    const float* bn3_v = (const float*)d_in[24];
    const float* fc_w  = (const float*)d_in[25];
    const float* fc_b  = (const float*)d_in[26];
    float* out = (float*)d_out;

    char* wsb = (char*)d_ws;
    float* ws    = (float*)d_ws;
    float* dwt   = ws;                  // 864 f (transposed [tap][oc])
    float* bn1_s = ws + 864;
    float* bn1_t = ws + 896;
    float* bn2_s = ws + 928;
    float* bn2_t = ws + 992;
    float* bn3_s = ws + 1056;
    float* bn3_t = ws + 1184;
    float* feat  = ws + 1312;           // 4096 f
    unsigned short* wrep2 = (unsigned short*)(wsb + 32768);    // 18432 ush
    unsigned short* wrep3 = (unsigned short*)(wsb + 69632);    // 73728 ush
    unsigned short* act1  = (unsigned short*)(wsb + 262144);   // 25.7MB
    unsigned short* act2  = (unsigned short*)(wsb + 262144 + 25690112); // 12.8MB

    gen_small<<<1, 256, 0, stream>>>(
        wb, bb, conv2_b, conv3_b,
        bn1_g, bn1_b, bn1_m, bn1_v, bn2_g, bn2_b, bn2_m, bn2_v,
        bn3_g, bn3_b, bn3_m, bn3_v,
        bn1_s, bn1_t, bn2_s, bn2_t, bn3_s, bn3_t, feat);

    gen_dynw_repack<<<576, 256, 0, stream>>>(
        w1, b1, w2, b2, w3, b3, conv2_w, conv3_w, dwt, wrep2, wrep3);

    conv1_pool<<<dim3(7, 7, BATCH), 256, 0, stream>>>(
        x, dwt, bn1_s, bn1_t, act1);

    conv2_mfma<<<dim3(7, 7, BATCH), 256, 0, stream>>>(
        act1, wrep2, bn2_s, bn2_t, act2);

    conv3_mfma<<<dim3(4, 4, BATCH*2), 256, 0, stream>>>(
        act2, wrep3, bn3_s, bn3_t, feat);

    fc_kernel<<<(BATCH*100 + 255)/256, 256, 0, stream>>>(feat, fc_w, fc_b, out);
}

// Round 8
// 200.346 us; speedup vs baseline: 1.1901x; 1.1901x over previous
//
#include <hip/hip_runtime.h>
#include <hip/hip_bf16.h>

#define BATCH 32
#define HW1 224

typedef __attribute__((ext_vector_type(8))) short short8;
typedef __attribute__((ext_vector_type(4))) float floatx4;

static __device__ __forceinline__ unsigned short f2bf(float f) {
    unsigned int u = __float_as_uint(f);
    unsigned int r = (u + 0x7fffu + ((u >> 16) & 1u)) >> 16;   // RNE
    return (unsigned short)r;
}

// ---------------------------------------------------------------------------
// Kernel A2: blocks [0,216): recompute h1/h2 locally, dwt[tap][oc] = W3@h2+b3
// (wave-per-row dot). Blocks [216,576): conv2/conv3 weight repack to
// [tap][OC][IC] bf16. Block 576: BN const folding + feat zero (merged
// gen_small — saves a launch).
// ---------------------------------------------------------------------------
__global__ __launch_bounds__(256) void gen_dynw_repack(
    const float* __restrict__ w1, const float* __restrict__ b1,
    const float* __restrict__ w2, const float* __restrict__ b2,
    const float* __restrict__ w3, const float* __restrict__ b3,
    const float* __restrict__ conv2_w, const float* __restrict__ conv3_w,
    const float* __restrict__ wb, const float* __restrict__ bb,
    const float* __restrict__ conv2_b, const float* __restrict__ conv3_b,
    const float* __restrict__ bn1_g, const float* __restrict__ bn1_b,
    const float* __restrict__ bn1_m, const float* __restrict__ bn1_v,
    const float* __restrict__ bn2_g, const float* __restrict__ bn2_b,
    const float* __restrict__ bn2_m, const float* __restrict__ bn2_v,
    const float* __restrict__ bn3_g, const float* __restrict__ bn3_b,
    const float* __restrict__ bn3_m, const float* __restrict__ bn3_v,
    float* __restrict__ dwt,
    unsigned short* __restrict__ wrep2, unsigned short* __restrict__ wrep3,
    float* __restrict__ bn1_s, float* __restrict__ bn1_t,
    float* __restrict__ bn2_s, float* __restrict__ bn2_t,
    float* __restrict__ bn3_s, float* __restrict__ bn3_t,
    float* __restrict__ feat)
{
    __shared__ float h1s[128];
    __shared__ float h2s[256];
    const int blk = blockIdx.x;
    const int t = threadIdx.x;
    if (blk < 216) {
        if (t < 128) {
            float s = b1[t] + w1[t*3+0] + w1[t*3+1] + w1[t*3+2];
            h1s[t] = fmaxf(s, 0.f);
        }
        __syncthreads();
        {
            float s = b2[t];
            const float* wr = w2 + (size_t)t*128;
#pragma unroll 4
            for (int k = 0; k < 128; k += 4) {
                float4 wv = *(const float4*)(wr + k);
                s = fmaf(wv.x, h1s[k  ], s);
                s = fmaf(wv.y, h1s[k+1], s);
                s = fmaf(wv.z, h1s[k+2], s);
                s = fmaf(wv.w, h1s[k+3], s);
            }
            h2s[t] = fmaxf(s, 0.f);
        }
        __syncthreads();
        const int wave = t >> 6, lane = t & 63;
        const int row = blk*4 + wave;          // row = oc*27 + tap
        float4 wv = *(const float4*)(w3 + (size_t)row*256 + lane*4);
        float4 hv = *(const float4*)&h2s[lane*4];
        float s = wv.x*hv.x + wv.y*hv.y + wv.z*hv.z + wv.w*hv.w;
#pragma unroll
        for (int m = 1; m < 64; m <<= 1) s += __shfl_xor(s, m);
        if (lane == 0) {
            int oc = row / 27, tap = row - oc*27;   // tap = ic*9 + ky*3 + kx
            dwt[tap*32 + oc] = s + b3[row];
        }
    } else if (blk < 576) {
        const int i = (blk - 216)*256 + t;
        const int N2 = 9*64*32;   // 18432
        if (i < N2) {
            int tp = i / (64*32); int rem = i - tp*(64*32);
            int oc = rem >> 5, ic = rem & 31;
            wrep2[i] = f2bf(conv2_w[(oc*32 + ic)*9 + tp]);
        } else {
            int j = i - N2;       // j < 9*128*64
            int tp = j / (128*64); int rem = j - tp*(128*64);
            int oc = rem >> 6, ic = rem & 63;
            wrep3[j] = f2bf(conv3_w[(oc*64 + ic)*9 + tp]);
        }
    } else {
        if (t < 32) {
            float dynb = bb[t] + wb[t*3+0] + wb[t*3+1] + wb[t*3+2];
            float s = bn1_g[t] / sqrtf(bn1_v[t] + 1e-5f);
            bn1_s[t] = s;
            bn1_t[t] = (dynb - bn1_m[t]) * s + bn1_b[t];
        }
        if (t < 64) {
            float s = bn2_g[t] / sqrtf(bn2_v[t] + 1e-5f);
            bn2_s[t] = s;
            bn2_t[t] = (conv2_b[t] - bn2_m[t]) * s + bn2_b[t];
        }
        if (t < 128) {
            float s = bn3_g[t] / sqrtf(bn3_v[t] + 1e-5f);
            bn3_s[t] = s;
            bn3_t[t] = (conv3_b[t] - bn3_m[t]) * s + bn3_b[t];
        }
        for (int i = t; i < BATCH*128; i += 256) feat[i] = 0.f;
    }
}

// ---------------------------------------------------------------------------
// Kernel B: conv1 (3->32, 224x224, pad1) + bn + relu + 2x2 maxpool, via MFMA.
// R4-R7 lesson: VALU conv1 loses a register-allocation fight (allocator
// re-reads LDS per oc-group at any hint level). MFMA forces accumulators
// into the matrix pipe by construction.
// K packs all 27 taps: MFMA#1 K=32 = 4 quads x 2 taps x 4ch(pad);
//   quad0:(0,0),(0,1) quad1:(1,0),(1,1) quad2:(2,0),(2,1) quad3:(0,2),(1,2).
// MFMA#2: tap (2,2) in k=0..3, A zero for k>=4 so B may be garbage there.
// Input tile staged bf16 channel-last-pad4: sp[18][18][4]. Weights converted
// per-block from dwt (fp32, L1-hot) into LDS A/B panels.
// Block = 16x16 conv tile (224/16=14 exact, no masking); wave w owns rows
// 4w..4w+3; pooling pairs rows in-thread, cols via shfl_xor(1).
// Output bf16 channel-last act1[b][112][112][32].
// ---------------------------------------------------------------------------
__global__ __launch_bounds__(256) void conv1_pool(
    const float* __restrict__ x, const float* __restrict__ dwt,
    const float* __restrict__ bn_s, const float* __restrict__ bn_t,
    unsigned short* __restrict__ act1)
{
    __shared__ __align__(16) unsigned short sp[18*18*4];   // 2592 B
    __shared__ __align__(16) unsigned short swA[32*32];    // 2048 B
    __shared__ __align__(16) unsigned short swB[32*32];    // 2048 B

    const int tid = threadIdx.x;
    const int bx = blockIdx.x, by = blockIdx.y, b = blockIdx.z;
    const int gx0 = bx*16 - 1, gy0 = by*16 - 1;
    const float* xb = x + (size_t)b * 3 * HW1 * HW1;

    // zero weight panels (ws is poisoned 0xAA each launch; unwritten k must be 0)
    for (int i = tid; i < 1024; i += 256) { swA[i] = 0; swB[i] = 0; }

    // stage input tile: bf16 channel-last, ch padded to 4 (slot 3 = 0)
    for (int i = tid; i < 324; i += 256) {
        int r = i / 18, c = i - r*18;
        int gy = gy0 + r, gx = gx0 + c;
        unsigned short v0 = 0, v1 = 0, v2 = 0;
        if ((unsigned)gy < HW1 && (unsigned)gx < HW1) {
            const float* pp = xb + gy*HW1 + gx;
            v0 = f2bf(pp[0]);
            v1 = f2bf(pp[HW1*HW1]);
            v2 = f2bf(pp[2*HW1*HW1]);
        }
        unsigned int lo = (unsigned int)v0 | ((unsigned int)v1 << 16);
        unsigned int hi = (unsigned int)v2;
        *(uint2*)&sp[i*4] = make_uint2(lo, hi);
    }
    __syncthreads();   // panels zeroed + tile staged before scatter/use

    // scatter dyn weights into MFMA A-panels (864 scalars, L1-hot after blk 0)
    for (int i = tid; i < 864; i += 256) {
        int tap = i >> 5, oc = i & 31;     // dwt[i] with i = tap*32+oc
        int ic = tap / 9, kk = tap - ic*9;
        int ky = kk / 3, kx = kk - ky*3;
        unsigned short v = f2bf(dwt[i]);
        if (kk == 8)      swB[oc*32 + ic] = v;
        else if (kx < 2)  swA[oc*32 + ky*8 + kx*4 + ic] = v;
        else              swA[oc*32 + 3*8  + ky*4 + ic] = v;   // quad3, s=ky
    }
    __syncthreads();

    const int lane = tid & 63, wave = tid >> 6;
    const int n = lane & 15, quad = lane >> 4;

    // A-fragments: lane n = oc within tile; two oc-tiles (h=0,1)
    short8 afrA[2], afrB[2];
#pragma unroll
    for (int h = 0; h < 2; ++h) {
        afrA[h] = *(const short8*)&swA[((h*16 + n)*32) + quad*8];
        afrB[h] = *(const short8*)&swB[((h*16 + n)*32) + quad*8];
    }
    float4 sv[2], tv[2];
#pragma unroll
    for (int h = 0; h < 2; ++h) {
        sv[h] = *(const float4*)(bn_s + h*16 + quad*4);
        tv[h] = *(const float4*)(bn_t + h*16 + quad*4);
    }

    union U { short8 s8; uint2 u2[2]; };

    const int y0w = wave*4;
    float ev[2][4];

#pragma unroll
    for (int yi = 0; yi < 4; ++yi) {
        const int y = y0w + yi;
        // B-frag for MFMA#1: quads 0-2: rows y+quad, cols n,n+1;
        // quad 3: (y, n+2) and (y+1, n+2)
        int r0 = (quad < 3) ? (y + quad) : y;
        int c0 = (quad < 3) ? n : (n + 2);
        int r1 = (quad < 3) ? (y + quad) : (y + 1);
        int c1 = (quad < 3) ? (n + 1) : (n + 2);
        U bf1;
        bf1.u2[0] = *(const uint2*)&sp[(r0*18 + c0)*4];
        bf1.u2[1] = *(const uint2*)&sp[(r1*18 + c1)*4];
        // B-frag for MFMA#2: tap (2,2) = (y+2, n+2); only k<4 consumed
        U bf2;
        bf2.u2[0] = *(const uint2*)&sp[((y+2)*18 + (n+2))*4];
        bf2.u2[1] = bf2.u2[0];

        float vr[2][4];
#pragma unroll
        for (int h = 0; h < 2; ++h) {
            floatx4 acc = {0.f, 0.f, 0.f, 0.f};
            acc = __builtin_amdgcn_mfma_f32_16x16x32_bf16(afrA[h], bf1.s8, acc, 0, 0, 0);
            acc = __builtin_amdgcn_mfma_f32_16x16x32_bf16(afrB[h], bf2.s8, acc, 0, 0, 0);
            float sj[4] = {sv[h].x, sv[h].y, sv[h].z, sv[h].w};
            float tj[4] = {tv[h].x, tv[h].y, tv[h].z, tv[h].w};
#pragma unroll
            for (int j = 0; j < 4; ++j)
                vr[h][j] = fmaxf(fmaf(acc[j], sj[j], tj[j]), 0.f);
        }

        if ((yi & 1) == 0) {
#pragma unroll
            for (int h = 0; h < 2; ++h)
#pragma unroll
                for (int j = 0; j < 4; ++j) ev[h][j] = vr[h][j];
        } else {
            int py = by*8 + ((y0w + yi) >> 1);
            int px = bx*8 + (n >> 1);
            unsigned short* dstp =
                act1 + ((size_t)((b*112 + py)*112 + px))*32 + quad*4;
#pragma unroll
            for (int h = 0; h < 2; ++h) {
                unsigned int pk[2];
#pragma unroll
                for (int j = 0; j < 4; ++j) {
                    float m = fmaxf(vr[h][j], ev[h][j]);
                    m = fmaxf(m, __shfl_xor(m, 1));
                    unsigned short us = f2bf(m);
                    if (j & 1) pk[j >> 1] |= ((unsigned int)us) << 16;
                    else       pk[j >> 1]  = us;
                }
                if (!(n & 1)) *(uint2*)(dstp + h*16) = *(uint2*)pk;
            }
        }
    }
}

// ---------------------------------------------------------------------------
// Kernel C: conv2 (32->64, 112x112) bf16 MFMA + bn + relu + 2x2 maxpool.
// Rolling-row-window: 54 ds_read_b128/wave, 144 MFMA.
// ---------------------------------------------------------------------------
__global__ __launch_bounds__(256) void conv2_mfma(
    const unsigned short* __restrict__ act1,
    const unsigned short* __restrict__ wrep,
    const float* __restrict__ bn_s, const float* __restrict__ bn_t,
    unsigned short* __restrict__ act2)
{
    constexpr int IC = 32, OC = 64, H = 112;
    __shared__ __align__(16) short lds[4*18*18*8];   // [chunk][y][x][8ic]

    const int tid = threadIdx.x;
    const int b = blockIdx.z;
    const int cx0 = blockIdx.x*16, cy0 = blockIdx.y*16;
    const unsigned short* ab = act1 + (size_t)b*H*H*IC;

    for (int s = tid; s < 4*324; s += 256) {
        int ck = s / 324; int rem = s - ck*324;
        int y = rem / 18, xx = rem - y*18;
        int gy = cy0 - 1 + y, gx = cx0 - 1 + xx;
        uint4 v = {0,0,0,0};
        if ((unsigned)gy < H && (unsigned)gx < H)
            v = *(const uint4*)(ab + (size_t)(gy*H + gx)*IC + ck*8);
        *(uint4*)&lds[s*8] = v;
    }

    const int lane = tid & 63, wave = tid >> 6;
    const int n = lane & 15, quad = lane >> 4;
    const int oc0w = wave * 16;

    short8 afr[9];
#pragma unroll
    for (int t = 0; t < 9; ++t)
        afr[t] = *(const short8*)(wrep + (size_t)(t*OC + oc0w + n)*IC + quad*8);

    float4 sv = *(const float4*)(bn_s + oc0w + quad*4);
    float4 tv = *(const float4*)(bn_t + oc0w + quad*4);
    float sj[4] = {sv.x, sv.y, sv.z, sv.w};
    float tj[4] = {tv.x, tv.y, tv.z, tv.w};

    __syncthreads();

    floatx4 acc[3];
    float ev[4];

#pragma unroll
    for (int r = 0; r < 18; ++r) {
        const short* rp = &lds[((quad*18 + r)*18 + n)*8];
        short8 w0 = *(const short8*)(rp);
        short8 w1 = *(const short8*)(rp + 8);
        short8 w2 = *(const short8*)(rp + 16);

        if (r < 16) {
            floatx4 a = {0.f,0.f,0.f,0.f};
            a = __builtin_amdgcn_mfma_f32_16x16x32_bf16(afr[0], w0, a, 0, 0, 0);
            a = __builtin_amdgcn_mfma_f32_16x16x32_bf16(afr[1], w1, a, 0, 0, 0);
            a = __builtin_amdgcn_mfma_f32_16x16x32_bf16(afr[2], w2, a, 0, 0, 0);
            acc[r % 3] = a;
        }
        if (r >= 1 && r <= 16) {
            int y = r - 1;
            floatx4 a = acc[y % 3];
            a = __builtin_amdgcn_mfma_f32_16x16x32_bf16(afr[3], w0, a, 0, 0, 0);
            a = __builtin_amdgcn_mfma_f32_16x16x32_bf16(afr[4], w1, a, 0, 0, 0);
            a = __builtin_amdgcn_mfma_f32_16x16x32_bf16(afr[5], w2, a, 0, 0, 0);
            acc[y % 3] = a;
        }
        if (r >= 2) {
            int y = r - 2;
            floatx4 a = acc[y % 3];
            a = __builtin_amdgcn_mfma_f32_16x16x32_bf16(afr[6], w0, a, 0, 0, 0);
            a = __builtin_amdgcn_mfma_f32_16x16x32_bf16(afr[7], w1, a, 0, 0, 0);
            a = __builtin_amdgcn_mfma_f32_16x16x32_bf16(afr[8], w2, a, 0, 0, 0);

            float v[4];
#pragma unroll
            for (int j = 0; j < 4; ++j)
                v[j] = fmaxf(fmaf(a[j], sj[j], tj[j]), 0.f);

            if ((y & 1) == 0) {
#pragma unroll
                for (int j = 0; j < 4; ++j) ev[j] = v[j];
            } else {
                unsigned int pk[2];
#pragma unroll
                for (int j = 0; j < 4; ++j) {
                    float m = fmaxf(v[j], ev[j]);
                    m = fmaxf(m, __shfl_xor(m, 1));
                    unsigned short us = f2bf(m);
                    if (j & 1) pk[j >> 1] |= ((unsigned int)us) << 16;
                    else       pk[j >> 1]  = us;
                }
                if (!(n & 1)) {
                    int py = (cy0 >> 1) + (y >> 1), px = (cx0 >> 1) + (n >> 1);
                    unsigned short* dstp =
                        act2 + ((size_t)((b*56 + py)*56 + px))*OC + oc0w + quad*4;
                    *(uint2*)dstp = *(uint2*)pk;
                }
            }
        }
    }
}

// ---------------------------------------------------------------------------
// Kernel D: conv3 (64->128, 56x56) bf16 MFMA + bn + relu + spatial mean sum.
// ---------------------------------------------------------------------------
__global__ __launch_bounds__(256) void conv3_mfma(
    const unsigned short* __restrict__ act2,
    const unsigned short* __restrict__ wrep,
    const float* __restrict__ bn_s, const float* __restrict__ bn_t,
    float* __restrict__ feat)
{
    constexpr int IC = 64, OC = 128, H = 56;
    __shared__ __align__(16) short lds[8*18*18*8];

    const int tid = threadIdx.x;
    const int b = blockIdx.z >> 1, half = blockIdx.z & 1;
    const int cx0 = blockIdx.x*16, cy0 = blockIdx.y*16;
    const unsigned short* ab = act2 + (size_t)b*H*H*IC;

    for (int s = tid; s < 8*324; s += 256) {
        int ck = s / 324; int rem = s - ck*324;
        int y = rem / 18, xx = rem - y*18;
        int gy = cy0 - 1 + y, gx = cx0 - 1 + xx;
        uint4 v = {0,0,0,0};
        if ((unsigned)gy < H && (unsigned)gx < H)
            v = *(const uint4*)(ab + (size_t)(gy*H + gx)*IC + ck*8);
        *(uint4*)&lds[s*8] = v;
    }

    const int lane = tid & 63, wave = tid >> 6;
    const int n = lane & 15, quad = lane >> 4;
    const int oc0w = half*64 + wave*16;

    short8 afr[18];
#pragma unroll
    for (int t = 0; t < 9; ++t)
#pragma unroll
        for (int kc = 0; kc < 2; ++kc)
            afr[t*2 + kc] = *(const short8*)(wrep + (size_t)(t*OC + oc0w + n)*IC + kc*32 + quad*8);

    float4 sv = *(const float4*)(bn_s + oc0w + quad*4);
    float4 tv = *(const float4*)(bn_t + oc0w + quad*4);

    __syncthreads();

    float sum[4] = {0.f, 0.f, 0.f, 0.f};
    const bool vx = (cx0 + n) < H;
    const int ymax = (H - cy0) < 16 ? (H - cy0) : 16;
    float sj[4] = {sv.x, sv.y, sv.z, sv.w};
    float tj[4] = {tv.x, tv.y, tv.z, tv.w};

    for (int y = 0; y < ymax; ++y) {
        floatx4 acc0 = {0.f,0.f,0.f,0.f};
        floatx4 acc1 = {0.f,0.f,0.f,0.f};
#pragma unroll
        for (int ky = 0; ky < 3; ++ky)
#pragma unroll
            for (int kx = 0; kx < 3; ++kx) {
                int t = ky*3 + kx;
                short8 b0 = *(const short8*)&lds[(((0*4 + quad)*18 + y+ky)*18 + n+kx)*8];
                short8 b1 = *(const short8*)&lds[(((1*4 + quad)*18 + y+ky)*18 + n+kx)*8];
                acc0 = __builtin_amdgcn_mfma_f32_16x16x32_bf16(afr[t*2+0], b0, acc0, 0, 0, 0);
                acc1 = __builtin_amdgcn_mfma_f32_16x16x32_bf16(afr[t*2+1], b1, acc1, 0, 0, 0);
            }
        if (vx) {
#pragma unroll
            for (int j = 0; j < 4; ++j)
                sum[j] += fmaxf(fmaf(acc0[j] + acc1[j], sj[j], tj[j]), 0.f);
        }
    }
#pragma unroll
    for (int j = 0; j < 4; ++j) {
        sum[j] += __shfl_xor(sum[j], 1);
        sum[j] += __shfl_xor(sum[j], 2);
        sum[j] += __shfl_xor(sum[j], 4);
        sum[j] += __shfl_xor(sum[j], 8);
    }
    if (n == 0) {
#pragma unroll
        for (int j = 0; j < 4; ++j)
            atomicAdd(&feat[b*128 + oc0w + quad*4 + j], sum[j]);
    }
}

// ---------------------------------------------------------------------------
// Kernel E: FC head.
// ---------------------------------------------------------------------------
__global__ __launch_bounds__(256) void fc_kernel(
    const float* __restrict__ feat, const float* __restrict__ fc_w,
    const float* __restrict__ fc_b, float* __restrict__ out)
{
    int i = blockIdx.x * 256 + threadIdx.x;
    if (i >= BATCH*100) return;
    int b = i / 100, n = i - b*100;
    const float* f = feat + b*128;
    const float* w = fc_w + n*128;
    float s = 0.f;
#pragma unroll 4
    for (int k = 0; k < 128; ++k) s = fmaf(f[k], w[k], s);
    out[i] = s * (1.f/3136.f) + fc_b[n];
}

extern "C" void kernel_launch(void* const* d_in, const int* in_sizes, int n_in,
                              void* d_out, int out_size, void* d_ws, size_t ws_size,
                              hipStream_t stream)
{
    const float* x       = (const float*)d_in[0];
    const float* w1      = (const float*)d_in[1];
    const float* b1      = (const float*)d_in[2];
    const float* w2      = (const float*)d_in[3];
    const float* b2      = (const float*)d_in[4];
    const float* w3      = (const float*)d_in[5];
    const float* b3      = (const float*)d_in[6];
    const float* wb      = (const float*)d_in[7];
    const float* bb      = (const float*)d_in[8];
    const float* conv2_w = (const float*)d_in[9];
    const float* conv2_b = (const float*)d_in[10];
    const float* conv3_w = (const float*)d_in[11];
    const float* conv3_b = (const float*)d_in[12];
    const float* bn1_g = (const float*)d_in[13];
    const float* bn1_b = (const float*)d_in[14];
    const float* bn1_m = (const float*)d_in[15];
    const float* bn1_v = (const float*)d_in[16];
    const float* bn2_g = (const float*)d_in[17];
    const float* bn2_b = (const float*)d_in[18];
    const float* bn2_m = (const float*)d_in[19];
    const float* bn2_v = (const float*)d_in[20];
    const float* bn3_g = (const float*)d_in[21];
    const float* bn3_b = (const float*)d_in[22];
    const float* bn3_m = (const float*)d_in[23];
    const float* bn3_v = (const float*)d_in[24];
    const float* fc_w  = (const float*)d_in[25];
    const float* fc_b  = (const float*)d_in[26];
    float* out = (float*)d_out;

    char* wsb = (char*)d_ws;
    float* ws    = (float*)d_ws;
    float* dwt   = ws;                  // 864 f ([tap][oc])
    float* bn1_s = ws + 864;
    float* bn1_t = ws + 896;
    float* bn2_s = ws + 928;
    float* bn2_t = ws + 992;
    float* bn3_s = ws + 1056;
    float* bn3_t = ws + 1184;
    float* feat  = ws + 1312;           // 4096 f
    unsigned short* wrep2 = (unsigned short*)(wsb + 32768);    // 18432 ush
    unsigned short* wrep3 = (unsigned short*)(wsb + 69632);    // 73728 ush
    unsigned short* act1  = (unsigned short*)(wsb + 262144);   // 25.7MB
    unsigned short* act2  = (unsigned short*)(wsb + 262144 + 25690112); // 12.8MB

    gen_dynw_repack<<<577, 256, 0, stream>>>(
        w1, b1, w2, b2, w3, b3, conv2_w, conv3_w,
        wb, bb, conv2_b, conv3_b,
        bn1_g, bn1_b, bn1_m, bn1_v, bn2_g, bn2_b, bn2_m, bn2_v,
        bn3_g, bn3_b, bn3_m, bn3_v,
        dwt, wrep2, wrep3,
        bn1_s, bn1_t, bn2_s, bn2_t, bn3_s, bn3_t, feat);

    conv1_pool<<<dim3(14, 14, BATCH), 256, 0, stream>>>(
        x, dwt, bn1_s, bn1_t, act1);

    conv2_mfma<<<dim3(7, 7, BATCH), 256, 0, stream>>>(
        act1, wrep2, bn2_s, bn2_t, act2);

    conv3_mfma<<<dim3(4, 4, BATCH*2), 256, 0, stream>>>(
        act2, wrep3, bn3_s, bn3_t, feat);

    fc_kernel<<<(BATCH*100 + 255)/256, 256, 0, stream>>>(feat, fc_w, fc_b, out);
}

// Round 9
// 190.375 us; speedup vs baseline: 1.2524x; 1.0524x over previous
//
#include <hip/hip_runtime.h>
#include <hip/hip_bf16.h>

#define BATCH 32
#define HW1 224

typedef __attribute__((ext_vector_type(8))) short short8;
typedef __attribute__((ext_vector_type(4))) float floatx4;

static __device__ __forceinline__ unsigned short f2bf(float f) {
    unsigned int u = __float_as_uint(f);
    unsigned int r = (u + 0x7fffu + ((u >> 16) & 1u)) >> 16;   // RNE
    return (unsigned short)r;
}

// ---------------------------------------------------------------------------
// Kernel A2: blocks [0,216): recompute h1/h2 locally, dwt[tap][oc] = W3@h2+b3
// (wave-per-row dot). Blocks [216,576): conv2/conv3 weight repack to
// [tap][OC][IC] bf16. Block 576: BN const folding + feat zero.
// ---------------------------------------------------------------------------
__global__ __launch_bounds__(256) void gen_dynw_repack(
    const float* __restrict__ w1, const float* __restrict__ b1,
    const float* __restrict__ w2, const float* __restrict__ b2,
    const float* __restrict__ w3, const float* __restrict__ b3,
    const float* __restrict__ conv2_w, const float* __restrict__ conv3_w,
    const float* __restrict__ wb, const float* __restrict__ bb,
    const float* __restrict__ conv2_b, const float* __restrict__ conv3_b,
    const float* __restrict__ bn1_g, const float* __restrict__ bn1_b,
    const float* __restrict__ bn1_m, const float* __restrict__ bn1_v,
    const float* __restrict__ bn2_g, const float* __restrict__ bn2_b,
    const float* __restrict__ bn2_m, const float* __restrict__ bn2_v,
    const float* __restrict__ bn3_g, const float* __restrict__ bn3_b,
    const float* __restrict__ bn3_m, const float* __restrict__ bn3_v,
    float* __restrict__ dwt,
    unsigned short* __restrict__ wrep2, unsigned short* __restrict__ wrep3,
    float* __restrict__ bn1_s, float* __restrict__ bn1_t,
    float* __restrict__ bn2_s, float* __restrict__ bn2_t,
    float* __restrict__ bn3_s, float* __restrict__ bn3_t,
    float* __restrict__ feat)
{
    __shared__ float h1s[128];
    __shared__ float h2s[256];
    const int blk = blockIdx.x;
    const int t = threadIdx.x;
    if (blk < 216) {
        if (t < 128) {
            float s = b1[t] + w1[t*3+0] + w1[t*3+1] + w1[t*3+2];
            h1s[t] = fmaxf(s, 0.f);
        }
        __syncthreads();
        {
            float s = b2[t];
            const float* wr = w2 + (size_t)t*128;
#pragma unroll 4
            for (int k = 0; k < 128; k += 4) {
                float4 wv = *(const float4*)(wr + k);
                s = fmaf(wv.x, h1s[k  ], s);
                s = fmaf(wv.y, h1s[k+1], s);
                s = fmaf(wv.z, h1s[k+2], s);
                s = fmaf(wv.w, h1s[k+3], s);
            }
            h2s[t] = fmaxf(s, 0.f);
        }
        __syncthreads();
        const int wave = t >> 6, lane = t & 63;
        const int row = blk*4 + wave;          // row = oc*27 + tap
        float4 wv = *(const float4*)(w3 + (size_t)row*256 + lane*4);
        float4 hv = *(const float4*)&h2s[lane*4];
        float s = wv.x*hv.x + wv.y*hv.y + wv.z*hv.z + wv.w*hv.w;
#pragma unroll
        for (int m = 1; m < 64; m <<= 1) s += __shfl_xor(s, m);
        if (lane == 0) {
            int oc = row / 27, tap = row - oc*27;   // tap = ic*9 + ky*3 + kx
            dwt[tap*32 + oc] = s + b3[row];
        }
    } else if (blk < 576) {
        const int i = (blk - 216)*256 + t;
        const int N2 = 9*64*32;   // 18432
        if (i < N2) {
            int tp = i / (64*32); int rem = i - tp*(64*32);
            int oc = rem >> 5, ic = rem & 31;
            wrep2[i] = f2bf(conv2_w[(oc*32 + ic)*9 + tp]);
        } else {
            int j = i - N2;       // j < 9*128*64
            int tp = j / (128*64); int rem = j - tp*(128*64);
            int oc = rem >> 6, ic = rem & 63;
            wrep3[j] = f2bf(conv3_w[(oc*64 + ic)*9 + tp]);
        }
    } else {
        if (t < 32) {
            float dynb = bb[t] + wb[t*3+0] + wb[t*3+1] + wb[t*3+2];
            float s = bn1_g[t] / sqrtf(bn1_v[t] + 1e-5f);
            bn1_s[t] = s;
            bn1_t[t] = (dynb - bn1_m[t]) * s + bn1_b[t];
        }
        if (t < 64) {
            float s = bn2_g[t] / sqrtf(bn2_v[t] + 1e-5f);
            bn2_s[t] = s;
            bn2_t[t] = (conv2_b[t] - bn2_m[t]) * s + bn2_b[t];
        }
        if (t < 128) {
            float s = bn3_g[t] / sqrtf(bn3_v[t] + 1e-5f);
            bn3_s[t] = s;
            bn3_t[t] = (conv3_b[t] - bn3_m[t]) * s + bn3_b[t];
        }
        for (int i = t; i < BATCH*128; i += 256) feat[i] = 0.f;
    }
}

// ---------------------------------------------------------------------------
// Kernel B: conv1 (3->32, 224x224, pad1) + bn + relu + 2x2 maxpool, via MFMA.
// K packs all 27 taps (see R8). Output bf16 channel-last act1[b][112][112][32].
// ---------------------------------------------------------------------------
__global__ __launch_bounds__(256) void conv1_pool(
    const float* __restrict__ x, const float* __restrict__ dwt,
    const float* __restrict__ bn_s, const float* __restrict__ bn_t,
    unsigned short* __restrict__ act1)
{
    __shared__ __align__(16) unsigned short sp[18*18*4];   // 2592 B
    __shared__ __align__(16) unsigned short swA[32*32];    // 2048 B
    __shared__ __align__(16) unsigned short swB[32*32];    // 2048 B

    const int tid = threadIdx.x;
    const int bx = blockIdx.x, by = blockIdx.y, b = blockIdx.z;
    const int gx0 = bx*16 - 1, gy0 = by*16 - 1;
    const float* xb = x + (size_t)b * 3 * HW1 * HW1;

    for (int i = tid; i < 1024; i += 256) { swA[i] = 0; swB[i] = 0; }

    for (int i = tid; i < 324; i += 256) {
        int r = i / 18, c = i - r*18;
        int gy = gy0 + r, gx = gx0 + c;
        unsigned short v0 = 0, v1 = 0, v2 = 0;
        if ((unsigned)gy < HW1 && (unsigned)gx < HW1) {
            const float* pp = xb + gy*HW1 + gx;
            v0 = f2bf(pp[0]);
            v1 = f2bf(pp[HW1*HW1]);
            v2 = f2bf(pp[2*HW1*HW1]);
        }
        unsigned int lo = (unsigned int)v0 | ((unsigned int)v1 << 16);
        unsigned int hi = (unsigned int)v2;
        *(uint2*)&sp[i*4] = make_uint2(lo, hi);
    }
    __syncthreads();

    for (int i = tid; i < 864; i += 256) {
        int tap = i >> 5, oc = i & 31;
        int ic = tap / 9, kk = tap - ic*9;
        int ky = kk / 3, kx = kk - ky*3;
        unsigned short v = f2bf(dwt[i]);
        if (kk == 8)      swB[oc*32 + ic] = v;
        else if (kx < 2)  swA[oc*32 + ky*8 + kx*4 + ic] = v;
        else              swA[oc*32 + 3*8  + ky*4 + ic] = v;
    }
    __syncthreads();

    const int lane = tid & 63, wave = tid >> 6;
    const int n = lane & 15, quad = lane >> 4;

    short8 afrA[2], afrB[2];
#pragma unroll
    for (int h = 0; h < 2; ++h) {
        afrA[h] = *(const short8*)&swA[((h*16 + n)*32) + quad*8];
        afrB[h] = *(const short8*)&swB[((h*16 + n)*32) + quad*8];
    }
    float4 sv[2], tv[2];
#pragma unroll
    for (int h = 0; h < 2; ++h) {
        sv[h] = *(const float4*)(bn_s + h*16 + quad*4);
        tv[h] = *(const float4*)(bn_t + h*16 + quad*4);
    }

    union U { short8 s8; uint2 u2[2]; };

    const int y0w = wave*4;
    float ev[2][4];

#pragma unroll
    for (int yi = 0; yi < 4; ++yi) {
        const int y = y0w + yi;
        int r0 = (quad < 3) ? (y + quad) : y;
        int c0 = (quad < 3) ? n : (n + 2);
        int r1 = (quad < 3) ? (y + quad) : (y + 1);
        int c1 = (quad < 3) ? (n + 1) : (n + 2);
        U bf1;
        bf1.u2[0] = *(const uint2*)&sp[(r0*18 + c0)*4];
        bf1.u2[1] = *(const uint2*)&sp[(r1*18 + c1)*4];
        U bf2;
        bf2.u2[0] = *(const uint2*)&sp[((y+2)*18 + (n+2))*4];
        bf2.u2[1] = bf2.u2[0];

        float vr[2][4];
#pragma unroll
        for (int h = 0; h < 2; ++h) {
            floatx4 acc = {0.f, 0.f, 0.f, 0.f};
            acc = __builtin_amdgcn_mfma_f32_16x16x32_bf16(afrA[h], bf1.s8, acc, 0, 0, 0);
            acc = __builtin_amdgcn_mfma_f32_16x16x32_bf16(afrB[h], bf2.s8, acc, 0, 0, 0);
            float sj[4] = {sv[h].x, sv[h].y, sv[h].z, sv[h].w};
            float tj[4] = {tv[h].x, tv[h].y, tv[h].z, tv[h].w};
#pragma unroll
            for (int j = 0; j < 4; ++j)
                vr[h][j] = fmaxf(fmaf(acc[j], sj[j], tj[j]), 0.f);
        }

        if ((yi & 1) == 0) {
#pragma unroll
            for (int h = 0; h < 2; ++h)
#pragma unroll
                for (int j = 0; j < 4; ++j) ev[h][j] = vr[h][j];
        } else {
            int py = by*8 + ((y0w + yi) >> 1);
            int px = bx*8 + (n >> 1);
            unsigned short* dstp =
                act1 + ((size_t)((b*112 + py)*112 + px))*32 + quad*4;
#pragma unroll
            for (int h = 0; h < 2; ++h) {
                unsigned int pk[2];
#pragma unroll
                for (int j = 0; j < 4; ++j) {
                    float m = fmaxf(vr[h][j], ev[h][j]);
                    m = fmaxf(m, __shfl_xor(m, 1));
                    unsigned short us = f2bf(m);
                    if (j & 1) pk[j >> 1] |= ((unsigned int)us) << 16;
                    else       pk[j >> 1]  = us;
                }
                if (!(n & 1)) *(uint2*)(dstp + h*16) = *(uint2*)pk;
            }
        }
    }
}

// ---------------------------------------------------------------------------
// Kernel C: conv2 (32->64, 112x112) bf16 MFMA + bn + relu + 2x2 maxpool.
// Rolling-row-window: 54 ds_read_b128/wave, 144 MFMA.
// ---------------------------------------------------------------------------
__global__ __launch_bounds__(256) void conv2_mfma(
    const unsigned short* __restrict__ act1,
    const unsigned short* __restrict__ wrep,
    const float* __restrict__ bn_s, const float* __restrict__ bn_t,
    unsigned short* __restrict__ act2)
{
    constexpr int IC = 32, OC = 64, H = 112;
    __shared__ __align__(16) short lds[4*18*18*8];   // [chunk][y][x][8ic]

    const int tid = threadIdx.x;
    const int b = blockIdx.z;
    const int cx0 = blockIdx.x*16, cy0 = blockIdx.y*16;
    const unsigned short* ab = act1 + (size_t)b*H*H*IC;

    for (int s = tid; s < 4*324; s += 256) {
        int ck = s / 324; int rem = s - ck*324;
        int y = rem / 18, xx = rem - y*18;
        int gy = cy0 - 1 + y, gx = cx0 - 1 + xx;
        uint4 v = {0,0,0,0};
        if ((unsigned)gy < H && (unsigned)gx < H)
            v = *(const uint4*)(ab + (size_t)(gy*H + gx)*IC + ck*8);
        *(uint4*)&lds[s*8] = v;
    }

    const int lane = tid & 63, wave = tid >> 6;
    const int n = lane & 15, quad = lane >> 4;
    const int oc0w = wave * 16;

    short8 afr[9];
#pragma unroll
    for (int t = 0; t < 9; ++t)
        afr[t] = *(const short8*)(wrep + (size_t)(t*OC + oc0w + n)*IC + quad*8);

    float4 sv = *(const float4*)(bn_s + oc0w + quad*4);
    float4 tv = *(const float4*)(bn_t + oc0w + quad*4);
    float sj[4] = {sv.x, sv.y, sv.z, sv.w};
    float tj[4] = {tv.x, tv.y, tv.z, tv.w};

    __syncthreads();

    floatx4 acc[3];
    float ev[4];

#pragma unroll
    for (int r = 0; r < 18; ++r) {
        const short* rp = &lds[((quad*18 + r)*18 + n)*8];
        short8 w0 = *(const short8*)(rp);
        short8 w1 = *(const short8*)(rp + 8);
        short8 w2 = *(const short8*)(rp + 16);

        if (r < 16) {
            floatx4 a = {0.f,0.f,0.f,0.f};
            a = __builtin_amdgcn_mfma_f32_16x16x32_bf16(afr[0], w0, a, 0, 0, 0);
            a = __builtin_amdgcn_mfma_f32_16x16x32_bf16(afr[1], w1, a, 0, 0, 0);
            a = __builtin_amdgcn_mfma_f32_16x16x32_bf16(afr[2], w2, a, 0, 0, 0);
            acc[r % 3] = a;
        }
        if (r >= 1 && r <= 16) {
            int y = r - 1;
            floatx4 a = acc[y % 3];
            a = __builtin_amdgcn_mfma_f32_16x16x32_bf16(afr[3], w0, a, 0, 0, 0);
            a = __builtin_amdgcn_mfma_f32_16x16x32_bf16(afr[4], w1, a, 0, 0, 0);
            a = __builtin_amdgcn_mfma_f32_16x16x32_bf16(afr[5], w2, a, 0, 0, 0);
            acc[y % 3] = a;
        }
        if (r >= 2) {
            int y = r - 2;
            floatx4 a = acc[y % 3];
            a = __builtin_amdgcn_mfma_f32_16x16x32_bf16(afr[6], w0, a, 0, 0, 0);
            a = __builtin_amdgcn_mfma_f32_16x16x32_bf16(afr[7], w1, a, 0, 0, 0);
            a = __builtin_amdgcn_mfma_f32_16x16x32_bf16(afr[8], w2, a, 0, 0, 0);

            float v[4];
#pragma unroll
            for (int j = 0; j < 4; ++j)
                v[j] = fmaxf(fmaf(a[j], sj[j], tj[j]), 0.f);

            if ((y & 1) == 0) {
#pragma unroll
                for (int j = 0; j < 4; ++j) ev[j] = v[j];
            } else {
                unsigned int pk[2];
#pragma unroll
                for (int j = 0; j < 4; ++j) {
                    float m = fmaxf(v[j], ev[j]);
                    m = fmaxf(m, __shfl_xor(m, 1));
                    unsigned short us = f2bf(m);
                    if (j & 1) pk[j >> 1] |= ((unsigned int)us) << 16;
                    else       pk[j >> 1]  = us;
                }
                if (!(n & 1)) {
                    int py = (cy0 >> 1) + (y >> 1), px = (cx0 >> 1) + (n >> 1);
                    unsigned short* dstp =
                        act2 + ((size_t)((b*56 + py)*56 + px))*OC + oc0w + quad*4;
                    *(uint2*)dstp = *(uint2*)pk;
                }
            }
        }
    }
}

// ---------------------------------------------------------------------------
// Kernel D: conv3 (64->128, 56x56) bf16 MFMA + bn + relu + spatial mean sum.
// NOW rolling-row-window (reads/wave 288->96) + exact y-tile=14 (4x14=56,
// zero masked rows; MFMA 288->252/wave; LDS 41.5->36.9 KB).
// ---------------------------------------------------------------------------
__global__ __launch_bounds__(256) void conv3_mfma(
    const unsigned short* __restrict__ act2,
    const unsigned short* __restrict__ wrep,
    const float* __restrict__ bn_s, const float* __restrict__ bn_t,
    float* __restrict__ feat)
{
    constexpr int IC = 64, OC = 128, H = 56;
    __shared__ __align__(16) short lds[8*16*18*8];   // [chunk][row16][col18][8ic]

    const int tid = threadIdx.x;
    const int b = blockIdx.z >> 1, half = blockIdx.z & 1;
    const int cx0 = blockIdx.x*16, cy0 = blockIdx.y*14;
    const unsigned short* ab = act2 + (size_t)b*H*H*IC;

    for (int s = tid; s < 8*16*18; s += 256) {
        int ck = s / (16*18); int rem = s - ck*(16*18);
        int y = rem / 18, xx = rem - y*18;
        int gy = cy0 - 1 + y, gx = cx0 - 1 + xx;
        uint4 v = {0,0,0,0};
        if ((unsigned)gy < H && (unsigned)gx < H)
            v = *(const uint4*)(ab + (size_t)(gy*H + gx)*IC + ck*8);
        *(uint4*)&lds[s*8] = v;
    }

    const int lane = tid & 63, wave = tid >> 6;
    const int n = lane & 15, quad = lane >> 4;
    const int oc0w = half*64 + wave*16;

    short8 afr[18];   // [tap][kc]
#pragma unroll
    for (int t = 0; t < 9; ++t)
#pragma unroll
        for (int kc = 0; kc < 2; ++kc)
            afr[t*2 + kc] = *(const short8*)(wrep + (size_t)(t*OC + oc0w + n)*IC + kc*32 + quad*8);

    float4 sv = *(const float4*)(bn_s + oc0w + quad*4);
    float4 tv = *(const float4*)(bn_t + oc0w + quad*4);
    float sj[4] = {sv.x, sv.y, sv.z, sv.w};
    float tj[4] = {tv.x, tv.y, tv.z, tv.w};

    __syncthreads();

    float sum[4] = {0.f, 0.f, 0.f, 0.f};
    const bool vx = (cx0 + n) < H;
    floatx4 acc[3];

#pragma unroll
    for (int r = 0; r < 16; ++r) {
        const short* p0 = &lds[((quad*16     + r)*18 + n)*8];
        const short* p1 = &lds[(((4+quad)*16 + r)*18 + n)*8];
        short8 a0 = *(const short8*)(p0);
        short8 a1 = *(const short8*)(p0 + 8);
        short8 a2 = *(const short8*)(p0 + 16);
        short8 b0 = *(const short8*)(p1);
        short8 b1 = *(const short8*)(p1 + 8);
        short8 b2 = *(const short8*)(p1 + 16);

        if (r < 14) {                    // ky=0 for out y=r (init)
            floatx4 a = {0.f,0.f,0.f,0.f};
            a = __builtin_amdgcn_mfma_f32_16x16x32_bf16(afr[0], a0, a, 0, 0, 0);
            a = __builtin_amdgcn_mfma_f32_16x16x32_bf16(afr[1], b0, a, 0, 0, 0);
            a = __builtin_amdgcn_mfma_f32_16x16x32_bf16(afr[2], a1, a, 0, 0, 0);
            a = __builtin_amdgcn_mfma_f32_16x16x32_bf16(afr[3], b1, a, 0, 0, 0);
            a = __builtin_amdgcn_mfma_f32_16x16x32_bf16(afr[4], a2, a, 0, 0, 0);
            a = __builtin_amdgcn_mfma_f32_16x16x32_bf16(afr[5], b2, a, 0, 0, 0);
            acc[r % 3] = a;
        }
        if (r >= 1 && r <= 14) {         // ky=1 for out y=r-1
            int y = r - 1;
            floatx4 a = acc[y % 3];
            a = __builtin_amdgcn_mfma_f32_16x16x32_bf16(afr[6],  a0, a, 0, 0, 0);
            a = __builtin_amdgcn_mfma_f32_16x16x32_bf16(afr[7],  b0, a, 0, 0, 0);
            a = __builtin_amdgcn_mfma_f32_16x16x32_bf16(afr[8],  a1, a, 0, 0, 0);
            a = __builtin_amdgcn_mfma_f32_16x16x32_bf16(afr[9],  b1, a, 0, 0, 0);
            a = __builtin_amdgcn_mfma_f32_16x16x32_bf16(afr[10], a2, a, 0, 0, 0);
            a = __builtin_amdgcn_mfma_f32_16x16x32_bf16(afr[11], b2, a, 0, 0, 0);
            acc[y % 3] = a;
        }
        if (r >= 2) {                    // ky=2 for out y=r-2, then finalize
            int y = r - 2;
            floatx4 a = acc[y % 3];
            a = __builtin_amdgcn_mfma_f32_16x16x32_bf16(afr[12], a0, a, 0, 0, 0);
            a = __builtin_amdgcn_mfma_f32_16x16x32_bf16(afr[13], b0, a, 0, 0, 0);
            a = __builtin_amdgcn_mfma_f32_16x16x32_bf16(afr[14], a1, a, 0, 0, 0);
            a = __builtin_amdgcn_mfma_f32_16x16x32_bf16(afr[15], b1, a, 0, 0, 0);
            a = __builtin_amdgcn_mfma_f32_16x16x32_bf16(afr[16], a2, a, 0, 0, 0);
            a = __builtin_amdgcn_mfma_f32_16x16x32_bf16(afr[17], b2, a, 0, 0, 0);
            if (vx) {
#pragma unroll
                for (int j = 0; j < 4; ++j)
                    sum[j] += fmaxf(fmaf(a[j], sj[j], tj[j]), 0.f);
            }
        }
    }
#pragma unroll
    for (int j = 0; j < 4; ++j) {
        sum[j] += __shfl_xor(sum[j], 1);
        sum[j] += __shfl_xor(sum[j], 2);
        sum[j] += __shfl_xor(sum[j], 4);
        sum[j] += __shfl_xor(sum[j], 8);
    }
    if (n == 0) {
#pragma unroll
        for (int j = 0; j < 4; ++j)
            atomicAdd(&feat[b*128 + oc0w + quad*4 + j], sum[j]);
    }
}

// ---------------------------------------------------------------------------
// Kernel E: FC head.
// ---------------------------------------------------------------------------
__global__ __launch_bounds__(256) void fc_kernel(
    const float* __restrict__ feat, const float* __restrict__ fc_w,
    const float* __restrict__ fc_b, float* __restrict__ out)
{
    int i = blockIdx.x * 256 + threadIdx.x;
    if (i >= BATCH*100) return;
    int b = i / 100, n = i - b*100;
    const float* f = feat + b*128;
    const float* w = fc_w + n*128;
    float s = 0.f;
#pragma unroll 4
    for (int k = 0; k < 128; ++k) s = fmaf(f[k], w[k], s);
    out[i] = s * (1.f/3136.f) + fc_b[n];
}

extern "C" void kernel_launch(void* const* d_in, const int* in_sizes, int n_in,
                              void* d_out, int out_size, void* d_ws, size_t ws_size,
                              hipStream_t stream)
{
    const float* x       = (const float*)d_in[0];
    const float* w1      = (const float*)d_in[1];
    const float* b1      = (const float*)d_in[2];
    const float* w2      = (const float*)d_in[3];
    const float* b2      = (const float*)d_in[4];
    const float* w3      = (const float*)d_in[5];
    const float* b3      = (const float*)d_in[6];
    const float* wb      = (const float*)d_in[7];
    const float* bb      = (const float*)d_in[8];
    const float* conv2_w = (const float*)d_in[9];
    const float* conv2_b = (const float*)d_in[10];
    const float* conv3_w = (const float*)d_in[11];
    const float* conv3_b = (const float*)d_in[12];
    const float* bn1_g = (const float*)d_in[13];
    const float* bn1_b = (const float*)d_in[14];
    const float* bn1_m = (const float*)d_in[15];
    const float* bn1_v = (const float*)d_in[16];
    const float* bn2_g = (const float*)d_in[17];
    const float* bn2_b = (const float*)d_in[18];
    const float* bn2_m = (const float*)d_in[19];
    const float* bn2_v = (const float*)d_in[20];
    const float* bn3_g = (const float*)d_in[21];
    const float* bn3_b = (const float*)d_in[22];
    const float* bn3_m = (const float*)d_in[23];
    const float* bn3_v = (const float*)d_in[24];
    const float* fc_w  = (const float*)d_in[25];
    const float* fc_b  = (const float*)d_in[26];
    float* out = (float*)d_out;

    char* wsb = (char*)d_ws;
    float* ws    = (float*)d_ws;
    float* dwt   = ws;                  // 864 f ([tap][oc])
    float* bn1_s = ws + 864;
    float* bn1_t = ws + 896;
    float* bn2_s = ws + 928;
    float* bn2_t = ws + 992;
    float* bn3_s = ws + 1056;
    float* bn3_t = ws + 1184;
    float* feat  = ws + 1312;           // 4096 f
    unsigned short* wrep2 = (unsigned short*)(wsb + 32768);    // 18432 ush
    unsigned short* wrep3 = (unsigned short*)(wsb + 69632);    // 73728 ush
    unsigned short* act1  = (unsigned short*)(wsb + 262144);   // 25.7MB
    unsigned short* act2  = (unsigned short*)(wsb + 262144 + 25690112); // 12.8MB

    gen_dynw_repack<<<577, 256, 0, stream>>>(
        w1, b1, w2, b2, w3, b3, conv2_w, conv3_w,
        wb, bb, conv2_b, conv3_b,
        bn1_g, bn1_b, bn1_m, bn1_v, bn2_g, bn2_b, bn2_m, bn2_v,
        bn3_g, bn3_b, bn3_m, bn3_v,
        dwt, wrep2, wrep3,
        bn1_s, bn1_t, bn2_s, bn2_t, bn3_s, bn3_t, feat);

    conv1_pool<<<dim3(14, 14, BATCH), 256, 0, stream>>>(
        x, dwt, bn1_s, bn1_t, act1);

    conv2_mfma<<<dim3(7, 7, BATCH), 256, 0, stream>>>(
        act1, wrep2, bn2_s, bn2_t, act2);

    conv3_mfma<<<dim3(4, 4, BATCH*2), 256, 0, stream>>>(
        act2, wrep3, bn3_s, bn3_t, feat);

    fc_kernel<<<(BATCH*100 + 255)/256, 256, 0, stream>>>(feat, fc_w, fc_b, out);
}